// Round 3
// baseline (162.346 us; speedup 1.0000x reference)
//
#include <hip/hip_runtime.h>

// CTR-GC: N=64, C_IN=C_OUT=128, T=128, V=25, REL=16. fp32 in/out, bf16 MFMA inside.
// k_prep: reads x ONCE: computes mean over T AND emits x as bf16 MFMA B-frags
//         to global Xf (52.4 MB, L3-resident for k_main).
// k_adj : adjacency built in LDS (bf16 B-frag order) + W3 -> bf16 frag order (global)
// k_main: phase A is now a pure linear Xf->LDS copy (no gather, no f2bf).
//         16 waves, split-j acc (13 frags = 52 regs), x3 repack union buffer.

#define NB   64
#define CIN  128
#define COUT 128
#define TT   128
#define VV   25
#define REL  16

#define JT 25                        // j-tiles (j = t_local*25+v, 400 = 25*16)
#define KT 4                         // k-tiles of 32
#define XF_BYTES (JT * KT * 1024)    // 102,400 per (n,tb) block
#define X3_STRIDE 1040               // x3 row stride (65*16B, de-banked)
#define LDS_BYTES (COUT * X3_STRIDE) // 133,120 (union: X frags alive only pre-repack)

typedef __attribute__((ext_vector_type(8))) short bf16x8;
typedef __attribute__((ext_vector_type(4))) float f32x4;

__device__ inline short f2bf(float f) {   // RNE f32->bf16 (finite inputs)
    unsigned u = __float_as_uint(f);
    u += 0x7fff + ((u >> 16) & 1);
    return (short)(u >> 16);
}

// ---------------- K1: x -> (mean over T, bf16 frag-ordered Xf) ----------------
// grid (KT = 4, N = 64), 256 thr. Block (kt, n): 32 c-rows, loop over 8 t-blocks.
__launch_bounds__(256)
__global__ void k_prep(const float* __restrict__ x, float* __restrict__ xm,
                       char* __restrict__ Xf) {
    __shared__ float tile[32 * 400];   // 51.2 KB: 32 c-rows x (16 t x 25 v)
    int tid = threadIdx.x;
    int kt = blockIdx.x, n = blockIdx.y;
    int c0 = kt * 32;
    float msum0 = 0.f, msum1 = 0.f, msum2 = 0.f, msum3 = 0.f;

    for (int tb = 0; tb < 8; ++tb) {
        __syncthreads();   // previous iteration's tile reads done
        const float* src = x + (((size_t)n * CIN + c0) * TT + tb * 16) * VV;
        for (int i = tid; i < 3200; i += 256) {
            int c = i / 100, q = i - c * 100;
            *reinterpret_cast<float4*>(&tile[c * 400 + q * 4]) =
                *reinterpret_cast<const float4*>(src + (size_t)c * (TT * VV) + q * 4);
        }
        __syncthreads();
        // mean partials: 800 (c,v) pairs, p = tid + 256*i
        {
            int p = tid;
            {   int c = p / 25, v = p - c * 25;
                const float* r = &tile[c * 400 + v];
                float s = 0.f;
#pragma unroll
                for (int t = 0; t < 16; ++t) s += r[t * 25];
                msum0 += s; }
            p = tid + 256;
            {   int c = p / 25, v = p - c * 25;
                const float* r = &tile[c * 400 + v];
                float s = 0.f;
#pragma unroll
                for (int t = 0; t < 16; ++t) s += r[t * 25];
                msum1 += s; }
            p = tid + 512;
            {   int c = p / 25, v = p - c * 25;
                const float* r = &tile[c * 400 + v];
                float s = 0.f;
#pragma unroll
                for (int t = 0; t < 16; ++t) s += r[t * 25];
                msum2 += s; }
            p = tid + 768;
            if (p < 800) {
                int c = p / 25, v = p - c * 25;
                const float* r = &tile[c * 400 + v];
                float s = 0.f;
#pragma unroll
                for (int t = 0; t < 16; ++t) s += r[t * 25];
                msum3 += s; }
        }
        // emit bf16 frags: 1600 chunks of 16 B for this (n, tb, kt)
        char* dst = Xf + (size_t)(n * 8 + tb) * XF_BYTES + (size_t)kt * 25 * 1024;
        for (int ch = tid; ch < 1600; ch += 256) {
            int l = ch & 63, jt = ch >> 6;
            int j = jt * 16 + (l & 15);
            int cl = 8 * (l >> 4);
            bf16x8 v;
#pragma unroll
            for (int b = 0; b < 8; ++b) v[b] = f2bf(tile[(cl + b) * 400 + j]);
            *reinterpret_cast<bf16x8*>(dst + (size_t)ch * 16) = v;
        }
    }
    // write means (sum over all 128 t accumulated across tb)
    {
        int p = tid;
        { int c = p / 25, v = p - c * 25;
          xm[((size_t)n * CIN + c0 + c) * VV + v] = msum0 * (1.0f / TT); }
        p = tid + 256;
        { int c = p / 25, v = p - c * 25;
          xm[((size_t)n * CIN + c0 + c) * VV + v] = msum1 * (1.0f / TT); }
        p = tid + 512;
        { int c = p / 25, v = p - c * 25;
          xm[((size_t)n * CIN + c0 + c) * VV + v] = msum2 * (1.0f / TT); }
        p = tid + 768;
        if (p < 800) {
            int c = p / 25, v = p - c * 25;
            xm[((size_t)n * CIN + c0 + c) * VV + v] = msum3 * (1.0f / TT);
        }
    }
}

// ---------------- K2: adjacency -> bf16 B-fragment order (LDS-staged) ----------------
// grid (N, 4): n, o-chunk of 32. adjT region per (n,o): 2048 B.
// The 4 blocks with n==0 additionally emit W3 in bf16 A-frag order to W3f (32 KB).
__global__ void k_adj(const float* __restrict__ xm,
                      const float* __restrict__ A, const float* __restrict__ alphap,
                      const float* __restrict__ W1, const float* __restrict__ b1,
                      const float* __restrict__ W2, const float* __restrict__ b2,
                      const float* __restrict__ W4, const float* __restrict__ b4,
                      const float* __restrict__ W3, char* __restrict__ W3f,
                      char* __restrict__ adjT) {
    __shared__ char adjS[32 * 2048];   // 64 KB staging
    __shared__ float xms[CIN * VV];
    __shared__ float W1s[REL * CIN];
    __shared__ float W2s[REL * CIN];
    __shared__ float x1s[REL * VV];
    __shared__ float x2s[REL * VV];
    __shared__ float W4s[32 * REL];
    __shared__ float b4s[32];

    int tid = threadIdx.x;
    int n = blockIdx.x;
    int o0 = blockIdx.y * 32;

    // W3 -> frag order, once (n==0 blocks; 4 blocks x 512 chunks = 2048 chunks)
    if (n == 0) {
#pragma unroll
        for (int pass = 0; pass < 2; ++pass) {
            int chunk = blockIdx.y * 512 + pass * 256 + tid;
            int l = chunk & 63;
            int frag = chunk >> 6;                 // ct*4 + kt
            int ct = frag >> 2, kt = frag & 3;
            int c = ct * 16 + (l & 15);
            int kb = kt * 32 + 8 * (l >> 4);
            const float4 f0 = *reinterpret_cast<const float4*>(&W3[(size_t)c * CIN + kb]);
            const float4 f1 = *reinterpret_cast<const float4*>(&W3[(size_t)c * CIN + kb + 4]);
            bf16x8 vv;
            vv[0] = f2bf(f0.x); vv[1] = f2bf(f0.y); vv[2] = f2bf(f0.z); vv[3] = f2bf(f0.w);
            vv[4] = f2bf(f1.x); vv[5] = f2bf(f1.y); vv[6] = f2bf(f1.z); vv[7] = f2bf(f1.w);
            *reinterpret_cast<bf16x8*>(W3f + (size_t)chunk * 16) = vv;
        }
    }

    for (int i = tid; i < 16384; i += 256) reinterpret_cast<float*>(adjS)[i] = 0.f;
    for (int i = tid; i < CIN * VV; i += 256) xms[i] = xm[(size_t)n * CIN * VV + i];
    for (int i = tid; i < REL * CIN; i += 256) { W1s[i] = W1[i]; W2s[i] = W2[i]; }
    for (int i = tid; i < 32 * REL; i += 256) W4s[i] = W4[o0 * REL + i];
    if (tid < 32) b4s[tid] = b4[o0 + tid];
    __syncthreads();

    for (int task = tid; task < 2 * REL * VV; task += 256) {
        int rv = task % (REL * VV);
        int which = task / (REL * VV);
        int r = rv / VV, v = rv % VV;
        const float* Ws = which ? W2s : W1s;
        float s = 0.f;
#pragma unroll 8
        for (int c = 0; c < CIN; ++c) s = fmaf(Ws[r * CIN + c], xms[c * VV + v], s);
        s += which ? b2[r] : b1[r];
        (which ? x2s : x1s)[rv] = s;
    }
    __syncthreads();

    float alpha = alphap[0];
    for (int p = tid; p < VV * VV; p += 256) {
        int v = p / VV, u = p % VV;
        float d[REL];
#pragma unroll
        for (int r = 0; r < REL; ++r) d[r] = tanhf(x1s[r * VV + v] - x2s[r * VV + u]);
        float Avu = A[v * VV + u];
        // B-frag offset: b_frag[b] = adj[v = 8*(l>>4)+b][u = ut*16 + (l&15)]
        int off = (u >> 4) * 1024 + (((u & 15) + 16 * (v >> 3)) * 16) + (v & 7) * 2;
        for (int oo = 0; oo < 32; ++oo) {
            float s = 0.f;
#pragma unroll
            for (int r = 0; r < REL; ++r) s = fmaf(W4s[oo * REL + r], d[r], s);
            float val = alpha * (s + b4s[oo]) + Avu;
            *(short*)(adjS + oo * 2048 + off) = f2bf(val);
        }
    }
    __syncthreads();

    float4* dst = reinterpret_cast<float4*>(adjT + (size_t)(n * COUT + o0) * 2048);
    const float4* src = reinterpret_cast<const float4*>(adjS);
    for (int i = tid; i < 4096; i += 256) dst[i] = src[i];
}

// ---------------- K3: two fused MFMA GEMMs (16 waves, split-j acc) ----------------
// grid (T/16 = 8, N = 64), 1024 threads. Wave w: ct = w>>1, j-half = w&1.
__launch_bounds__(1024)
__global__ void k_main(const char* __restrict__ Xf, const char* __restrict__ W3f,
                       const float* __restrict__ b3, const char* __restrict__ adjT,
                       float* __restrict__ out) {
    __shared__ __align__(16) char lds[LDS_BYTES];   // 133,120 B

    int tid = threadIdx.x;
    int tb = blockIdx.x, n = blockIdx.y;
    int lane = tid & 63, w = tid >> 6;
    int g = lane >> 4, lr = lane & 15;
    int ct = w >> 1, jh = w & 1;
    int jt0 = jh ? 13 : 0;
    int njt = jh ? 12 : 13;

    // ---- Phase A: linear copy Xf -> LDS (6400 x 16 B, fully coalesced) ----
    const char* xfb = Xf + (size_t)(n * 8 + tb) * XF_BYTES;
#pragma unroll
    for (int q = 0; q < 7; ++q) {
        int chunk = tid + q * 1024;
        if (chunk < JT * KT * 64)
            *reinterpret_cast<bf16x8*>(lds + (size_t)chunk * 16) =
                *reinterpret_cast<const bf16x8*>(xfb + (size_t)chunk * 16);
    }
    __syncthreads();

    // ---- Phase B: GEMM1  x3 = W3 @ X  (this wave: 16 c-rows x its j-half) ----
    f32x4 acc[13];
#pragma unroll
    for (int u = 0; u < 13; ++u) acc[u] = f32x4{0.f, 0.f, 0.f, 0.f};
#pragma unroll
    for (int kt = 0; kt < KT; ++kt) {
        bf16x8 a = *reinterpret_cast<const bf16x8*>(
            W3f + (size_t)((ct * 4 + kt) * 64 + lane) * 16);
#pragma unroll
        for (int u = 0; u < 13; ++u) {
            if (u < njt) {
                int jt = jt0 + u;
                bf16x8 bx = *reinterpret_cast<const bf16x8*>(
                    lds + (size_t)((kt * JT + jt) * 64 + lane) * 16);
                acc[u] = __builtin_amdgcn_mfma_f32_16x16x32_bf16(a, bx, acc[u], 0, 0, 0);
            }
        }
    }
    __syncthreads();   // all Xf reads done before repack overwrites

    // ---- Phase C: x3 (+b3) -> bf16 A-frag order, full 128-row buffer ----
    int cbase = ct * 16 + 4 * g;
    float bv[4];
#pragma unroll
    for (int r = 0; r < 4; ++r) bv[r] = b3[cbase + r];
#pragma unroll
    for (int u = 0; u < 13; ++u) {
        if (u < njt) {
            int j = (jt0 + u) * 16 + lr;
            int t = j / 25, v = j - t * 25;
            int off = (t + 16 * (v >> 3)) * 16 + (v & 7) * 2;
#pragma unroll
            for (int r = 0; r < 4; ++r)
                *(short*)(lds + (size_t)(cbase + r) * X3_STRIDE + off) =
                    f2bf(acc[u][r] + bv[r]);
        }
    }
    // zero v = 25..31 pad slots: 128 rows x 112 shorts = 14336 = 14 * 1024
#pragma unroll
    for (int z = 0; z < 14; ++z) {
        int idx = tid + z * 1024;
        int c = idx / 112;
        int rem = idx - c * 112;
        int t = rem / 7, qq = rem - t * 7;
        *(short*)(lds + (size_t)c * X3_STRIDE + (t + 48) * 16 + 2 + qq * 2) = 0;
    }
    __syncthreads();   // rows assembled by wave pairs -> block barrier

    // ---- Phase D: GEMM2  out = x3 @ adj  (8 c-rows per wave) ----
    const char* adjTb = adjT + (size_t)(n * COUT) * 2048;
    int t0 = tb * 16;
#pragma unroll
    for (int cc = 0; cc < 8; ++cc) {
        int c = w * 8 + cc;
        bf16x8 a = *reinterpret_cast<const bf16x8*>(lds + (size_t)c * X3_STRIDE + lane * 16);
        const bf16x8* bp = reinterpret_cast<const bf16x8*>(adjTb + (size_t)c * 2048);
        bf16x8 b0 = bp[lane];
        bf16x8 b1 = bp[64 + lane];
        f32x4 z = {0.f, 0.f, 0.f, 0.f};
        f32x4 d0 = __builtin_amdgcn_mfma_f32_16x16x32_bf16(a, b0, z, 0, 0, 0);
        f32x4 d1 = __builtin_amdgcn_mfma_f32_16x16x32_bf16(a, b1, z, 0, 0, 0);
        float* ob = out + ((size_t)(n * COUT + c) * TT + t0) * VV;
#pragma unroll
        for (int rr = 0; rr < 4; ++rr) {
            int t = 4 * g + rr;
            ob[(size_t)t * VV + lr] = d0[rr];
            if (lr < 9) ob[(size_t)t * VV + 16 + lr] = d1[rr];
        }
    }
}

extern "C" void kernel_launch(void* const* d_in, const int* in_sizes, int n_in,
                              void* d_out, int out_size, void* d_ws, size_t ws_size,
                              hipStream_t stream) {
    const float* x     = (const float*)d_in[0];
    const float* A     = (const float*)d_in[1];
    const float* alpha = (const float*)d_in[2];
    const float* W1    = (const float*)d_in[3];
    const float* b1    = (const float*)d_in[4];
    const float* W2    = (const float*)d_in[5];
    const float* b2    = (const float*)d_in[6];
    const float* W3    = (const float*)d_in[7];
    const float* b3    = (const float*)d_in[8];
    const float* W4    = (const float*)d_in[9];
    const float* b4    = (const float*)d_in[10];
    float* out = (float*)d_out;

    float* xm  = (float*)d_ws;                                // 819,200 B
    char* adjT = (char*)d_ws + 819200;                        // 16,777,216 B
    char* W3f  = (char*)d_ws + 819200 + 16777216;             // 32,768 B
    char* Xf   = (char*)d_ws + 819200 + 16777216 + 32768;     // 52,428,800 B

    k_prep<<<dim3(KT, NB), 256, 0, stream>>>(x, xm, Xf);
    k_adj<<<dim3(NB, 4), 256, 0, stream>>>(xm, A, alpha, W1, b1, W2, b2, W4, b4,
                                           W3, W3f, adjT);
    k_main<<<dim3(TT / 16, NB), 1024, 0, stream>>>(Xf, W3f, b3, adjT, out);
}

// Round 4
// 124.817 us; speedup vs baseline: 1.3007x; 1.3007x over previous
//
#include <hip/hip_runtime.h>

// CTR-GC: N=64, C_IN=C_OUT=128, T=128, V=25, REL=16. fp32 in/out, bf16 MFMA inside.
// k_prep: 2048 single-shot blocks. Each loads a 32c x 400j tile (swizzled LDS),
//         atomicAdds mean partials, emits bf16 MFMA B-frags to global Xf.
// k_adj : adjacency built in LDS (bf16 B-frag order) + W3 -> bf16 frag order (global)
// k_main: phase A is a pure linear Xf->LDS copy. 16 waves, split-j acc
//         (13 frags = 52 regs), x3 repack union buffer, GEMM2 = 8 c-rows/wave.

#define NB   64
#define CIN  128
#define COUT 128
#define TT   128
#define VV   25
#define REL  16

#define JT 25                        // j-tiles (j = t_local*25+v, 400 = 25*16)
#define KT 4                         // k-tiles of 32
#define XF_BYTES (JT * KT * 1024)    // 102,400 per (n,tb) block
#define X3_STRIDE 1040               // x3 row stride (65*16B, de-banked)
#define LDS_BYTES (COUT * X3_STRIDE) // 133,120 (union: X frags alive only pre-repack)
#define TSTRIDE 416                  // k_prep tile row stride (416 % 32 == 0)

typedef __attribute__((ext_vector_type(8))) short bf16x8;
typedef __attribute__((ext_vector_type(4))) float f32x4;

__device__ inline short f2bf(float f) {   // RNE f32->bf16 (finite inputs)
    unsigned u = __float_as_uint(f);
    u += 0x7fff + ((u >> 16) & 1);
    return (short)(u >> 16);
}

// ---------------- K1: x -> (mean partials via atomicAdd, bf16 frag Xf) ----------------
// grid (32, 64): blockIdx.x = kt*8 + tb. 256 thr. Single tile, one barrier.
__launch_bounds__(256)
__global__ void k_prep(const float* __restrict__ x, float* __restrict__ xm,
                       char* __restrict__ Xf) {
    __shared__ float tile[32 * TSTRIDE];   // 53,248 B
    int tid = threadIdx.x;
    int kt = blockIdx.x >> 3, tb = blockIdx.x & 7, n = blockIdx.y;
    int c0 = kt * 32;

    // load 32 rows x 400 floats, swizzled: j' = j ^ (((c>>3)&1)<<4)
    const float* src = x + (size_t)(n * CIN + c0) * 3200 + tb * 400;
#pragma unroll
    for (int p = 0; p < 13; ++p) {
        int i = tid + p * 256;
        if (i < 3200) {
            int c = i / 100, q = i - c * 100;
            int sw = ((c >> 3) & 1) << 4;
            *reinterpret_cast<float4*>(&tile[c * TSTRIDE + ((q * 4) ^ sw)]) =
                *reinterpret_cast<const float4*>(src + (size_t)c * 3200 + q * 4);
        }
    }
    __syncthreads();

    // mean partials over this block's 16 t -> atomicAdd into xm (pre-zeroed)
#pragma unroll
    for (int pp = 0; pp < 4; ++pp) {
        int p = tid + pp * 256;
        if (p < 800) {
            int c = p / 25, v = p - c * 25;
            int sw = ((c >> 3) & 1) << 4;
            float s = 0.f;
#pragma unroll
            for (int t = 0; t < 16; ++t) s += tile[c * TSTRIDE + ((t * 25 + v) ^ sw)];
            atomicAdd(&xm[((size_t)n * CIN + c0 + c) * VV + v], s * (1.0f / TT));
        }
    }

    // emit bf16 frags: 1600 chunks of 16 B (coalesced stores; 2-way LDS reads)
    char* dst = Xf + (size_t)(n * 8 + tb) * XF_BYTES + (size_t)kt * 25600;
    for (int ch = tid; ch < 1600; ch += 256) {
        int l = ch & 63, jt = ch >> 6;
        int j = jt * 16 + (l & 15);
        int cl = 8 * (l >> 4);
        int sw = ((l >> 4) & 1) << 4;   // rows cl..cl+7: (row>>3)&1 == (l>>4)&1
        bf16x8 v;
#pragma unroll
        for (int b = 0; b < 8; ++b)
            v[b] = f2bf(tile[(cl + b) * TSTRIDE + (j ^ sw)]);
        *reinterpret_cast<bf16x8*>(dst + (size_t)ch * 16) = v;
    }
}

// ---------------- K2: adjacency -> bf16 B-fragment order (LDS-staged) ----------------
// grid (N, 4): n, o-chunk of 32. adjT region per (n,o): 2048 B.
// The 4 blocks with n==0 additionally emit W3 in bf16 A-frag order to W3f (32 KB).
__global__ void k_adj(const float* __restrict__ xm,
                      const float* __restrict__ A, const float* __restrict__ alphap,
                      const float* __restrict__ W1, const float* __restrict__ b1,
                      const float* __restrict__ W2, const float* __restrict__ b2,
                      const float* __restrict__ W4, const float* __restrict__ b4,
                      const float* __restrict__ W3, char* __restrict__ W3f,
                      char* __restrict__ adjT) {
    __shared__ char adjS[32 * 2048];   // 64 KB staging
    __shared__ float xms[CIN * VV];
    __shared__ float W1s[REL * CIN];
    __shared__ float W2s[REL * CIN];
    __shared__ float x1s[REL * VV];
    __shared__ float x2s[REL * VV];
    __shared__ float W4s[32 * REL];
    __shared__ float b4s[32];

    int tid = threadIdx.x;
    int n = blockIdx.x;
    int o0 = blockIdx.y * 32;

    // W3 -> frag order, once (n==0 blocks; 4 blocks x 512 chunks = 2048 chunks)
    if (n == 0) {
#pragma unroll
        for (int pass = 0; pass < 2; ++pass) {
            int chunk = blockIdx.y * 512 + pass * 256 + tid;
            int l = chunk & 63;
            int frag = chunk >> 6;                 // ct*4 + kt
            int ct = frag >> 2, kt = frag & 3;
            int c = ct * 16 + (l & 15);
            int kb = kt * 32 + 8 * (l >> 4);
            const float4 f0 = *reinterpret_cast<const float4*>(&W3[(size_t)c * CIN + kb]);
            const float4 f1 = *reinterpret_cast<const float4*>(&W3[(size_t)c * CIN + kb + 4]);
            bf16x8 vv;
            vv[0] = f2bf(f0.x); vv[1] = f2bf(f0.y); vv[2] = f2bf(f0.z); vv[3] = f2bf(f0.w);
            vv[4] = f2bf(f1.x); vv[5] = f2bf(f1.y); vv[6] = f2bf(f1.z); vv[7] = f2bf(f1.w);
            *reinterpret_cast<bf16x8*>(W3f + (size_t)chunk * 16) = vv;
        }
    }

    for (int i = tid; i < 16384; i += 256) reinterpret_cast<float*>(adjS)[i] = 0.f;
    for (int i = tid; i < CIN * VV; i += 256) xms[i] = xm[(size_t)n * CIN * VV + i];
    for (int i = tid; i < REL * CIN; i += 256) { W1s[i] = W1[i]; W2s[i] = W2[i]; }
    for (int i = tid; i < 32 * REL; i += 256) W4s[i] = W4[o0 * REL + i];
    if (tid < 32) b4s[tid] = b4[o0 + tid];
    __syncthreads();

    for (int task = tid; task < 2 * REL * VV; task += 256) {
        int rv = task % (REL * VV);
        int which = task / (REL * VV);
        int r = rv / VV, v = rv % VV;
        const float* Ws = which ? W2s : W1s;
        float s = 0.f;
#pragma unroll 8
        for (int c = 0; c < CIN; ++c) s = fmaf(Ws[r * CIN + c], xms[c * VV + v], s);
        s += which ? b2[r] : b1[r];
        (which ? x2s : x1s)[rv] = s;
    }
    __syncthreads();

    float alpha = alphap[0];
    for (int p = tid; p < VV * VV; p += 256) {
        int v = p / VV, u = p % VV;
        float d[REL];
#pragma unroll
        for (int r = 0; r < REL; ++r) d[r] = tanhf(x1s[r * VV + v] - x2s[r * VV + u]);
        float Avu = A[v * VV + u];
        // B-frag offset: b_frag[b] = adj[v = 8*(l>>4)+b][u = ut*16 + (l&15)]
        int off = (u >> 4) * 1024 + (((u & 15) + 16 * (v >> 3)) * 16) + (v & 7) * 2;
        for (int oo = 0; oo < 32; ++oo) {
            float s = 0.f;
#pragma unroll
            for (int r = 0; r < REL; ++r) s = fmaf(W4s[oo * REL + r], d[r], s);
            float val = alpha * (s + b4s[oo]) + Avu;
            *(short*)(adjS + oo * 2048 + off) = f2bf(val);
        }
    }
    __syncthreads();

    float4* dst = reinterpret_cast<float4*>(adjT + (size_t)(n * COUT + o0) * 2048);
    const float4* src = reinterpret_cast<const float4*>(adjS);
    for (int i = tid; i < 4096; i += 256) dst[i] = src[i];
}

// ---------------- K3: two fused MFMA GEMMs (16 waves, split-j acc) ----------------
// grid (T/16 = 8, N = 64), 1024 threads. Wave w: ct = w>>1, j-half = w&1.
__launch_bounds__(1024)
__global__ void k_main(const char* __restrict__ Xf, const char* __restrict__ W3f,
                       const float* __restrict__ b3, const char* __restrict__ adjT,
                       float* __restrict__ out) {
    __shared__ __align__(16) char lds[LDS_BYTES];   // 133,120 B

    int tid = threadIdx.x;
    int tb = blockIdx.x, n = blockIdx.y;
    int lane = tid & 63, w = tid >> 6;
    int g = lane >> 4, lr = lane & 15;
    int ct = w >> 1, jh = w & 1;
    int jt0 = jh ? 13 : 0;
    int njt = jh ? 12 : 13;

    // ---- Phase A: linear copy Xf -> LDS (6400 x 16 B, fully coalesced) ----
    const char* xfb = Xf + (size_t)(n * 8 + tb) * XF_BYTES;
#pragma unroll
    for (int q = 0; q < 7; ++q) {
        int chunk = tid + q * 1024;
        if (chunk < JT * KT * 64)
            *reinterpret_cast<bf16x8*>(lds + (size_t)chunk * 16) =
                *reinterpret_cast<const bf16x8*>(xfb + (size_t)chunk * 16);
    }
    __syncthreads();

    // ---- Phase B: GEMM1  x3 = W3 @ X  (this wave: 16 c-rows x its j-half) ----
    f32x4 acc[13];
#pragma unroll
    for (int u = 0; u < 13; ++u) acc[u] = f32x4{0.f, 0.f, 0.f, 0.f};
#pragma unroll
    for (int kt = 0; kt < KT; ++kt) {
        bf16x8 a = *reinterpret_cast<const bf16x8*>(
            W3f + (size_t)((ct * 4 + kt) * 64 + lane) * 16);
#pragma unroll
        for (int u = 0; u < 13; ++u) {
            if (u < njt) {
                int jt = jt0 + u;
                bf16x8 bx = *reinterpret_cast<const bf16x8*>(
                    lds + (size_t)((kt * JT + jt) * 64 + lane) * 16);
                acc[u] = __builtin_amdgcn_mfma_f32_16x16x32_bf16(a, bx, acc[u], 0, 0, 0);
            }
        }
    }
    __syncthreads();   // all Xf reads done before repack overwrites

    // ---- Phase C: x3 (+b3) -> bf16 A-frag order, full 128-row buffer ----
    int cbase = ct * 16 + 4 * g;
    float bv[4];
#pragma unroll
    for (int r = 0; r < 4; ++r) bv[r] = b3[cbase + r];
#pragma unroll
    for (int u = 0; u < 13; ++u) {
        if (u < njt) {
            int j = (jt0 + u) * 16 + lr;
            int t = j / 25, v = j - t * 25;
            int off = (t + 16 * (v >> 3)) * 16 + (v & 7) * 2;
#pragma unroll
            for (int r = 0; r < 4; ++r)
                *(short*)(lds + (size_t)(cbase + r) * X3_STRIDE + off) =
                    f2bf(acc[u][r] + bv[r]);
        }
    }
    // zero v = 25..31 pad slots: 128 rows x 112 shorts = 14336 = 14 * 1024
#pragma unroll
    for (int z = 0; z < 14; ++z) {
        int idx = tid + z * 1024;
        int c = idx / 112;
        int rem = idx - c * 112;
        int t = rem / 7, qq = rem - t * 7;
        *(short*)(lds + (size_t)c * X3_STRIDE + (t + 48) * 16 + 2 + qq * 2) = 0;
    }
    __syncthreads();   // rows assembled by wave pairs -> block barrier

    // ---- Phase D: GEMM2  out = x3 @ adj  (8 c-rows per wave) ----
    const char* adjTb = adjT + (size_t)(n * COUT) * 2048;
    int t0 = tb * 16;
#pragma unroll
    for (int cc = 0; cc < 8; ++cc) {
        int c = w * 8 + cc;
        bf16x8 a = *reinterpret_cast<const bf16x8*>(lds + (size_t)c * X3_STRIDE + lane * 16);
        const bf16x8* bp = reinterpret_cast<const bf16x8*>(adjTb + (size_t)c * 2048);
        bf16x8 b0 = bp[lane];
        bf16x8 b1 = bp[64 + lane];
        f32x4 z = {0.f, 0.f, 0.f, 0.f};
        f32x4 d0 = __builtin_amdgcn_mfma_f32_16x16x32_bf16(a, b0, z, 0, 0, 0);
        f32x4 d1 = __builtin_amdgcn_mfma_f32_16x16x32_bf16(a, b1, z, 0, 0, 0);
        float* ob = out + ((size_t)(n * COUT + c) * TT + t0) * VV;
#pragma unroll
        for (int rr = 0; rr < 4; ++rr) {
            int t = 4 * g + rr;
            ob[(size_t)t * VV + lr] = d0[rr];
            if (lr < 9) ob[(size_t)t * VV + 16 + lr] = d1[rr];
        }
    }
}

extern "C" void kernel_launch(void* const* d_in, const int* in_sizes, int n_in,
                              void* d_out, int out_size, void* d_ws, size_t ws_size,
                              hipStream_t stream) {
    const float* x     = (const float*)d_in[0];
    const float* A     = (const float*)d_in[1];
    const float* alpha = (const float*)d_in[2];
    const float* W1    = (const float*)d_in[3];
    const float* b1    = (const float*)d_in[4];
    const float* W2    = (const float*)d_in[5];
    const float* b2    = (const float*)d_in[6];
    const float* W3    = (const float*)d_in[7];
    const float* b3    = (const float*)d_in[8];
    const float* W4    = (const float*)d_in[9];
    const float* b4    = (const float*)d_in[10];
    float* out = (float*)d_out;

    float* xm  = (float*)d_ws;                                // 819,200 B
    char* adjT = (char*)d_ws + 819200;                        // 16,777,216 B
    char* W3f  = (char*)d_ws + 819200 + 16777216;             // 32,768 B
    char* Xf   = (char*)d_ws + 819200 + 16777216 + 32768;     // 52,428,800 B

    hipMemsetAsync(xm, 0, 819200, stream);                    // xm accumulated atomically
    k_prep<<<dim3(32, NB), 256, 0, stream>>>(x, xm, Xf);
    k_adj<<<dim3(NB, 4), 256, 0, stream>>>(xm, A, alpha, W1, b1, W2, b2, W4, b4,
                                           W3, W3f, adjT);
    k_main<<<dim3(TT / 16, NB), 1024, 0, stream>>>(Xf, W3f, b3, adjT, out);
}